// Round 16
// baseline (67.395 us; speedup 1.0000x reference)
//
#include <hip/hip_runtime.h>

// out[b,u] = tanh( exp( max_i x[b,i]*W[i,u] ) - 1 + bias[u] )
// exp monotonic -> max commutes -> max-times "GEMM" + transcendental epilogue.
//
// R16 = R15 with x moved from the SCALAR path to the VECTOR-memory path.
// R7-R15 established: s_load (out-of-order) forces full lgkmcnt(0) drains,
// ~250cy stall per ~128cy compute, and prefetch is structurally impossible.
// VMEM decrements vmcnt IN ISSUE ORDER -> partial waits -> the compiler can
// pipeline row t+1's loads under row t's compute. An opaque VGPR zero in the
// address defeats uniform-load scalarization (forces global_load_dwordx4,
// per-lane-identical addr = TA broadcast). 16 rows fully unrolled, no acc
// array (direct part write), 128-VGPR budget -> 4 waves/SIMD.

#define BATCH 2048
#define INDIM 512
#define UNITS 512

#define KC 32   // k-chunk per wave
#define RB 16   // rows per block
#define NW 16   // waves per block (NW*KC == INDIM)

typedef float v2f __attribute__((ext_vector_type(2)));

__global__ __launch_bounds__(1024, 4) void maxexp_kernel(
    const float* __restrict__ x,     // [BATCH][INDIM]
    const float* __restrict__ W,     // [INDIM][UNITS]
    const float* __restrict__ bias,  // [UNITS]
    float* __restrict__ out)         // [BATCH][UNITS]
{
    __shared__ float part[RB][NW][64];   // 64 KB

    // bijective XCD swizzle: XCD (f&7) owns 16 contiguous bands x all u-tiles.
    const int f   = blockIdx.x;                        // 0..1023
    const int bg  = (f & 7) * 16 + ((f >> 3) & 15);    // band 0..127
    const int ut  = f >> 7;                            // u-tile 0..7

    const int lane = threadIdx.x & 63;
    const int wv   = __builtin_amdgcn_readfirstlane(threadIdx.x >> 6); // 0..15
    const int u    = ut * 64 + lane;       // unit (per-lane)
    const int k0   = wv * KC;              // k-chunk base (uniform)
    const int b0   = bg * RB;              // first row (uniform)

    // ---- preload W chunk as v2f pairs ----
    v2f wp[KC / 2];
    {
        const float* wb = W + (size_t)k0 * UNITS + u;
#pragma unroll
        for (int j = 0; j < KC / 2; ++j) {
            v2f t;
            t.x = wb[(size_t)(2 * j)     * UNITS];
            t.y = wb[(size_t)(2 * j + 1) * UNITS];
            wp[j] = t;
        }
    }
#pragma unroll
    for (int j = 0; j < KC / 2; ++j) asm("" : "+v"(wp[j]));

    // opaque zero in a VGPR: defeats uniform-load scalarization so x goes
    // through global_load_dwordx4 (vmcnt path, in-order, pipelineable).
    int vz;
    asm("v_mov_b32 %0, 0" : "=v"(vz));
    const float* xbase = x + (size_t)b0 * INDIM + k0 + vz;

    // ---- 16 independent rows: 8x global_load_dwordx4 + 16 pk_mul + 16 max3
    //      compiler schedules loads of later rows under earlier compute ----
#pragma unroll
    for (int t = 0; t < RB; ++t) {
        const float4* xr = reinterpret_cast<const float4*>(xbase + (size_t)t * INDIM);
        float4 q[8];
#pragma unroll
        for (int j = 0; j < 8; ++j) q[j] = xr[j];

        float m0 = -3.4e38f, m1 = -3.4e38f;
#pragma unroll
        for (int j = 0; j < 8; ++j) {
            v2f a0, a1, p0, p1;
            a0.x = q[j].x; a0.y = q[j].y;
            a1.x = q[j].z; a1.y = q[j].w;
            asm("v_pk_mul_f32 %0, %1, %2" : "=v"(p0) : "v"(a0), "v"(wp[2 * j]));
            asm("v_pk_mul_f32 %0, %1, %2" : "=v"(p1) : "v"(a1), "v"(wp[2 * j + 1]));
            m0 = fmaxf(fmaxf(m0, p0.x), p0.y);   // -> v_max3_f32
            m1 = fmaxf(fmaxf(m1, p1.x), p1.y);
        }
        part[t][wv][lane] = fmaxf(m0, m1);   // straight to LDS; no acc array
    }

    __syncthreads();   // all partials ready

    // ---- wave wv: 16-way combine for row wv, epilogue, store ----
    {
        const int t = wv;
        float m = -3.4e38f;
#pragma unroll
        for (int j = 0; j < NW; j += 2)
            m = fmaxf(fmaxf(m, part[t][j][lane]), part[t][j + 1][lane]);
        const float pp = __expf(m) - 1.0f + bias[u];
        const float e  = __expf(2.0f * pp);
        out[(size_t)(b0 + t) * UNITS + u] = 1.0f - 2.0f / (e + 1.0f);
    }
}

extern "C" void kernel_launch(void* const* d_in, const int* in_sizes, int n_in,
                              void* d_out, int out_size, void* d_ws, size_t ws_size,
                              hipStream_t stream) {
    const float* x    = (const float*)d_in[0];
    const float* W    = (const float*)d_in[1];
    const float* bias = (const float*)d_in[2];
    float* out = (float*)d_out;

    dim3 grid(BATCH / RB * (UNITS / 64));   // 128 bands * 8 u-tiles = 1024
    dim3 block(1024);                       // 16 waves
    maxexp_kernel<<<grid, block, 0, stream>>>(x, W, bias, out);
}

// Round 17
// 25.391 us; speedup vs baseline: 2.6542x; 2.6542x over previous
//
#include <hip/hip_runtime.h>

// out[b,u] = tanh( exp( max_i x[b,i]*W[i,u] ) - 1 + bias[u] )
// exp monotonic -> max commutes -> max-times "GEMM" + transcendental epilogue.
//
// R17 = R15 with x batches loaded as s_load_dwordx16 (64B = 1 full cache line
// per request) instead of s_load_dwordx8 (2 requests/line). R13-R16 model:
// T = 9.4us fixed + W; W dominated by per-CU scalar-memory request
// throughput (~1024 K$-miss requests/CU/gen at ~25cy each). This halves the
// request count at identical bytes, drains, and VALU work.
//   Block = 16 waves x 64 units (lane = unit), RB = 16 rows, 16-way k-split.
//   Wave: W[wv*32..+31][u] as 16 v2f VGPR pairs; 2 rows of x batched into
//   4x v16f SGPR buffers per drain; v_pk_mul_f32 (x from SGPR pair) + max3.

#define BATCH 2048
#define INDIM 512
#define UNITS 512

#define KC 32   // k-chunk per wave
#define RB 16   // rows per block
#define NW 16   // waves per block (NW*KC == INDIM)

typedef float v2f  __attribute__((ext_vector_type(2)));
typedef float v16f __attribute__((ext_vector_type(16)));

__global__ __launch_bounds__(1024, 8) void maxexp_kernel(
    const float* __restrict__ x,     // [BATCH][INDIM]
    const float* __restrict__ W,     // [INDIM][UNITS]
    const float* __restrict__ bias,  // [UNITS]
    float* __restrict__ out)         // [BATCH][UNITS]
{
    __shared__ float part[RB][NW][64];   // 64 KB

    // bijective XCD swizzle: XCD (f&7) owns 16 contiguous bands x all u-tiles.
    const int f   = blockIdx.x;                        // 0..1023
    const int bg  = (f & 7) * 16 + ((f >> 3) & 15);    // band 0..127
    const int ut  = f >> 7;                            // u-tile 0..7

    const int lane = threadIdx.x & 63;
    const int wv   = __builtin_amdgcn_readfirstlane(threadIdx.x >> 6); // 0..15
    const int u    = ut * 64 + lane;       // unit (per-lane)
    const int k0   = wv * KC;              // k-chunk base (uniform)
    const int b0   = bg * RB;              // first row (uniform)

    // ---- preload W chunk as v2f pairs ----
    v2f wp[KC / 2];
    {
        const float* wb = W + (size_t)k0 * UNITS + u;
#pragma unroll
        for (int j = 0; j < KC / 2; ++j) {
            v2f t;
            t.x = wb[(size_t)(2 * j)     * UNITS];
            t.y = wb[(size_t)(2 * j + 1) * UNITS];
            wp[j] = t;
        }
    }
#pragma unroll
    for (int j = 0; j < KC / 2; ++j) asm("" : "+v"(wp[j]));

    const float* xb = x + (size_t)b0 * INDIM + k0;   // uniform base (128B aligned)

    float acc[RB];

#pragma unroll
    for (int p = 0; p < RB / 2; ++p) {
        // ---- batch-load 2 rows of x: 4 x s_load_dwordx16 (1 line each) ----
        const v16f xa0 = *reinterpret_cast<const v16f*>(xb + (size_t)(2 * p)     * INDIM);
        const v16f xa1 = *reinterpret_cast<const v16f*>(xb + (size_t)(2 * p)     * INDIM + 16);
        const v16f xc0 = *reinterpret_cast<const v16f*>(xb + (size_t)(2 * p + 1) * INDIM);
        const v16f xc1 = *reinterpret_cast<const v16f*>(xb + (size_t)(2 * p + 1) * INDIM + 16);
        __builtin_amdgcn_sched_barrier(0);   // all 4 loads issued before any use

        // ---- row 2p ----
        {
            float m0 = -3.4e38f, m1 = -3.4e38f;
#pragma unroll
            for (int j = 0; j < 4; ++j) {
                v2f a0, a1, p0, p1;
                a0.x = xa0[4 * j];     a0.y = xa0[4 * j + 1];
                a1.x = xa0[4 * j + 2]; a1.y = xa0[4 * j + 3];
                asm("v_pk_mul_f32 %0, %1, %2" : "=v"(p0) : "s"(a0), "v"(wp[2 * j]));
                asm("v_pk_mul_f32 %0, %1, %2" : "=v"(p1) : "s"(a1), "v"(wp[2 * j + 1]));
                m0 = fmaxf(fmaxf(m0, p0.x), p0.y);   // -> v_max3_f32
                m1 = fmaxf(fmaxf(m1, p1.x), p1.y);
            }
#pragma unroll
            for (int j = 0; j < 4; ++j) {
                v2f a0, a1, p0, p1;
                a0.x = xa1[4 * j];     a0.y = xa1[4 * j + 1];
                a1.x = xa1[4 * j + 2]; a1.y = xa1[4 * j + 3];
                asm("v_pk_mul_f32 %0, %1, %2" : "=v"(p0) : "s"(a0), "v"(wp[8 + 2 * j]));
                asm("v_pk_mul_f32 %0, %1, %2" : "=v"(p1) : "s"(a1), "v"(wp[8 + 2 * j + 1]));
                m0 = fmaxf(fmaxf(m0, p0.x), p0.y);
                m1 = fmaxf(fmaxf(m1, p1.x), p1.y);
            }
            acc[2 * p] = fmaxf(m0, m1);
        }
        // ---- row 2p+1 ----
        {
            float m0 = -3.4e38f, m1 = -3.4e38f;
#pragma unroll
            for (int j = 0; j < 4; ++j) {
                v2f a0, a1, p0, p1;
                a0.x = xc0[4 * j];     a0.y = xc0[4 * j + 1];
                a1.x = xc0[4 * j + 2]; a1.y = xc0[4 * j + 3];
                asm("v_pk_mul_f32 %0, %1, %2" : "=v"(p0) : "s"(a0), "v"(wp[2 * j]));
                asm("v_pk_mul_f32 %0, %1, %2" : "=v"(p1) : "s"(a1), "v"(wp[2 * j + 1]));
                m0 = fmaxf(fmaxf(m0, p0.x), p0.y);
                m1 = fmaxf(fmaxf(m1, p1.x), p1.y);
            }
#pragma unroll
            for (int j = 0; j < 4; ++j) {
                v2f a0, a1, p0, p1;
                a0.x = xc1[4 * j];     a0.y = xc1[4 * j + 1];
                a1.x = xc1[4 * j + 2]; a1.y = xc1[4 * j + 3];
                asm("v_pk_mul_f32 %0, %1, %2" : "=v"(p0) : "s"(a0), "v"(wp[8 + 2 * j]));
                asm("v_pk_mul_f32 %0, %1, %2" : "=v"(p1) : "s"(a1), "v"(wp[8 + 2 * j + 1]));
                m0 = fmaxf(fmaxf(m0, p0.x), p0.y);
                m1 = fmaxf(fmaxf(m1, p1.x), p1.y);
            }
            acc[2 * p + 1] = fmaxf(m0, m1);
        }
    }

    // ---- 16-way cross-wave max combine via LDS (single barrier) ----
#pragma unroll
    for (int t = 0; t < RB; ++t) part[t][wv][lane] = acc[t];
    __syncthreads();

    // wave wv reduces + stores row wv
    {
        const int t = wv;
        float m = -3.4e38f;
#pragma unroll
        for (int j = 0; j < NW; j += 2)
            m = fmaxf(fmaxf(m, part[t][j][lane]), part[t][j + 1][lane]);
        const float pp = __expf(m) - 1.0f + bias[u];
        const float e  = __expf(2.0f * pp);
        out[(size_t)(b0 + t) * UNITS + u] = 1.0f - 2.0f / (e + 1.0f);
    }
}

extern "C" void kernel_launch(void* const* d_in, const int* in_sizes, int n_in,
                              void* d_out, int out_size, void* d_ws, size_t ws_size,
                              hipStream_t stream) {
    const float* x    = (const float*)d_in[0];
    const float* W    = (const float*)d_in[1];
    const float* bias = (const float*)d_in[2];
    float* out = (float*)d_out;

    dim3 grid(BATCH / RB * (UNITS / 64));   // 128 bands * 8 u-tiles = 1024
    dim3 block(1024);                       // 16 waves
    maxexp_kernel<<<grid, block, 0, stream>>>(x, W, bias, out);
}